// Round 7
// baseline (1214.380 us; speedup 1.0000x reference)
//
#include <hip/hip_runtime.h>

#define KDIM 512
#define TDIM 64
#define NWAVE 16
#define BLOCK 1024
#define LOG2E 1.4426950408889634f

__device__ __forceinline__ float fast_exp2(float v) { return __builtin_amdgcn_exp2f(v); }
__device__ __forceinline__ float fast_rcp(float v)  { return __builtin_amdgcn_rcpf(v); }

// ---- prefold: c2 = coeff*LOG2E, b2 = bias*LOG2E (2 MB in d_ws; cached, R4) ----
__global__ __launch_bounds__(256) void prefold_kernel(
    const float* __restrict__ coeff, const float* __restrict__ bias,
    float* __restrict__ c2, float* __restrict__ b2)
{
    const int i = blockIdx.x * 256 + threadIdx.x;   // float4 index
    const float4 c = ((const float4*)coeff)[i];
    const float4 b = ((const float4*)bias)[i];
    ((float4*)c2)[i] = make_float4(c.x * LOG2E, c.y * LOG2E, c.z * LOG2E, c.w * LOG2E);
    ((float4*)b2)[i] = make_float4(b.x * LOG2E, b.y * LOG2E, b.z * LOG2E, b.w * LOG2E);
}

// One workgroup per batch element; whole T-recurrence inside the kernel.
// R7: R4 layout (64-lane rows, 2 rows/iter) + 1-deep load pipeline (fits the
// 128-reg waves_per_eu(4,4) budget; R2's spill was under the phantom 64-reg
// cap) + 3 barriers/t-step instead of 4 (rtmp summed redundantly by all
// threads via LDS broadcast). Loads stay 1024B/wave coalesced (R5's 256B
// quarter-wave loads were the regression).
template <bool FOLDED>
__global__ __launch_bounds__(BLOCK)
__attribute__((amdgpu_waves_per_eu(4, 4)))
void hmm_forward_kernel(
    const float* __restrict__ x,           // [B, T]
    const float* __restrict__ prior_w,     // [K]
    const float* __restrict__ emission_w,  // [K, 2]
    const float* __restrict__ cc,          // [K,K] (= coeff*LOG2E if FOLDED)
    const float* __restrict__ bb,          // [K,K] (= bias*LOG2E  if FOLDED)
    float* __restrict__ out)               // [B, K]
{
    __shared__ float post[KDIM];
    __shared__ float em0s[KDIM];
    __shared__ float emds[KDIM];          // em1 - em0
    __shared__ float part[NWAVE][KDIM];   // per-wave pbe partials (32 KB)
    __shared__ float rtmp[8];
    __shared__ float xs[TDIM];

    const int b    = blockIdx.x;
    const int tid  = threadIdx.x;
    const int lane = tid & 63;
    const int wv   = tid >> 6;
    const int k0   = 4 * lane;            // lane covers k0..k0+3 and k0+256..k0+259

    if (tid < TDIM) xs[tid] = x[b * TDIM + tid];
    if (tid < KDIM) {
        const float w0 = emission_w[2 * tid + 0];
        const float w1 = emission_w[2 * tid + 1];
        const float e0 = 1.0f / (1.0f + fast_exp2((w1 - w0) * LOG2E));
        em0s[tid] = e0;
        emds[tid] = 1.0f - 2.0f * e0;
    }
    __syncthreads();

    // ---- t = 0 ----
    {
        const float x0 = xs[0];
        float v = 0.0f;
        if (tid < KDIM)
            v = fast_exp2(prior_w[tid] * LOG2E) * fmaf(x0, emds[tid], em0s[tid]);
        if (wv < 8) {
            float s = v;
            #pragma unroll
            for (int off = 1; off < 64; off <<= 1) s += __shfl_xor(s, off, 64);
            if (lane == 0) rtmp[wv] = s;
        }
        __syncthreads();
        float tot = ((rtmp[0] + rtmp[1]) + (rtmp[2] + rtmp[3]))
                  + ((rtmp[4] + rtmp[5]) + (rtmp[6] + rtmp[7]));
        const float rn = fast_rcp(tot);
        if (tid < KDIM) post[tid] = v * rn;
        __syncthreads();
    }

    // ---- steps t = 1 .. T-1 ----
    for (int t = 1; t < TDIM; ++t) {
        float acc[8];
        #pragma unroll
        for (int i = 0; i < 8; ++i) acc[i] = 0.0f;

        // wave wv: row pairs (jA = wv + 32*i, jB = jA + 16), i = 0..15
        const float* cA = cc + (size_t)wv * KDIM + k0;
        const float* bA = bb + (size_t)wv * KDIM + k0;

        // pipeline stage 0: preload iteration 0's 8 float4s
        float4 cA0 = *(const float4*)cA;
        float4 cA1 = *(const float4*)(cA + 256);
        float4 cB0 = *(const float4*)(cA + 16 * KDIM);
        float4 cB1 = *(const float4*)(cA + 16 * KDIM + 256);
        float4 bA0 = *(const float4*)bA;
        float4 bA1 = *(const float4*)(bA + 256);
        float4 bB0 = *(const float4*)(bA + 16 * KDIM);
        float4 bB1 = *(const float4*)(bA + 16 * KDIM + 256);

        #pragma unroll 1
        for (int i = 0; i < 16; ++i) {
            // issue next iteration's loads (clamped on last iter: L1-hot reload)
            const int adv = (i < 15) ? 32 * KDIM : 0;
            cA += adv; bA += adv;
            const float4 nA0 = *(const float4*)cA;
            const float4 nA1 = *(const float4*)(cA + 256);
            const float4 nB0 = *(const float4*)(cA + 16 * KDIM);
            const float4 nB1 = *(const float4*)(cA + 16 * KDIM + 256);
            const float4 mA0 = *(const float4*)bA;
            const float4 mA1 = *(const float4*)(bA + 256);
            const float4 mB0 = *(const float4*)(bA + 16 * KDIM);
            const float4 mB1 = *(const float4*)(bA + 16 * KDIM + 256);

            const float pA = post[wv + 32 * i];
            const float pB = post[wv + 16 + 32 * i];
            const float pAc = FOLDED ? pA : pA * LOG2E;
            const float pBc = FOLDED ? pB : pB * LOG2E;

            float eA0, eA1, eA2, eA3, eA4, eA5, eA6, eA7;
            float eB0, eB1, eB2, eB3, eB4, eB5, eB6, eB7;
            if (FOLDED) {
                eA0 = fast_exp2(fmaf(pAc, cA0.x, bA0.x));
                eA1 = fast_exp2(fmaf(pAc, cA0.y, bA0.y));
                eA2 = fast_exp2(fmaf(pAc, cA0.z, bA0.z));
                eA3 = fast_exp2(fmaf(pAc, cA0.w, bA0.w));
                eA4 = fast_exp2(fmaf(pAc, cA1.x, bA1.x));
                eA5 = fast_exp2(fmaf(pAc, cA1.y, bA1.y));
                eA6 = fast_exp2(fmaf(pAc, cA1.z, bA1.z));
                eA7 = fast_exp2(fmaf(pAc, cA1.w, bA1.w));
                eB0 = fast_exp2(fmaf(pBc, cB0.x, bB0.x));
                eB1 = fast_exp2(fmaf(pBc, cB0.y, bB0.y));
                eB2 = fast_exp2(fmaf(pBc, cB0.z, bB0.z));
                eB3 = fast_exp2(fmaf(pBc, cB0.w, bB0.w));
                eB4 = fast_exp2(fmaf(pBc, cB1.x, bB1.x));
                eB5 = fast_exp2(fmaf(pBc, cB1.y, bB1.y));
                eB6 = fast_exp2(fmaf(pBc, cB1.z, bB1.z));
                eB7 = fast_exp2(fmaf(pBc, cB1.w, bB1.w));
            } else {
                eA0 = fast_exp2(fmaf(pAc, cA0.x, bA0.x * LOG2E));
                eA1 = fast_exp2(fmaf(pAc, cA0.y, bA0.y * LOG2E));
                eA2 = fast_exp2(fmaf(pAc, cA0.z, bA0.z * LOG2E));
                eA3 = fast_exp2(fmaf(pAc, cA0.w, bA0.w * LOG2E));
                eA4 = fast_exp2(fmaf(pAc, cA1.x, bA1.x * LOG2E));
                eA5 = fast_exp2(fmaf(pAc, cA1.y, bA1.y * LOG2E));
                eA6 = fast_exp2(fmaf(pAc, cA1.z, bA1.z * LOG2E));
                eA7 = fast_exp2(fmaf(pAc, cA1.w, bA1.w * LOG2E));
                eB0 = fast_exp2(fmaf(pBc, cB0.x, bB0.x * LOG2E));
                eB1 = fast_exp2(fmaf(pBc, cB0.y, bB0.y * LOG2E));
                eB2 = fast_exp2(fmaf(pBc, cB0.z, bB0.z * LOG2E));
                eB3 = fast_exp2(fmaf(pBc, cB0.w, bB0.w * LOG2E));
                eB4 = fast_exp2(fmaf(pBc, cB1.x, bB1.x * LOG2E));
                eB5 = fast_exp2(fmaf(pBc, cB1.y, bB1.y * LOG2E));
                eB6 = fast_exp2(fmaf(pBc, cB1.z, bB1.z * LOG2E));
                eB7 = fast_exp2(fmaf(pBc, cB1.w, bB1.w * LOG2E));
            }

            float sA = ((eA0 + eA1) + (eA2 + eA3)) + ((eA4 + eA5) + (eA6 + eA7));
            float sB = ((eB0 + eB1) + (eB2 + eB3)) + ((eB4 + eB5) + (eB6 + eB7));
            #pragma unroll
            for (int off = 1; off < 64; off <<= 1) {   // dual independent chains
                sA += __shfl_xor(sA, off, 64);
                sB += __shfl_xor(sB, off, 64);
            }
            const float scA = pA * fast_rcp(sA);
            const float scB = pB * fast_rcp(sB);

            acc[0] = fmaf(scA, eA0, acc[0]); acc[0] = fmaf(scB, eB0, acc[0]);
            acc[1] = fmaf(scA, eA1, acc[1]); acc[1] = fmaf(scB, eB1, acc[1]);
            acc[2] = fmaf(scA, eA2, acc[2]); acc[2] = fmaf(scB, eB2, acc[2]);
            acc[3] = fmaf(scA, eA3, acc[3]); acc[3] = fmaf(scB, eB3, acc[3]);
            acc[4] = fmaf(scA, eA4, acc[4]); acc[4] = fmaf(scB, eB4, acc[4]);
            acc[5] = fmaf(scA, eA5, acc[5]); acc[5] = fmaf(scB, eB5, acc[5]);
            acc[6] = fmaf(scA, eA6, acc[6]); acc[6] = fmaf(scB, eB6, acc[6]);
            acc[7] = fmaf(scA, eA7, acc[7]); acc[7] = fmaf(scB, eB7, acc[7]);

            cA0 = nA0; cA1 = nA1; bA0 = mA0; bA1 = mA1;
            cB0 = nB0; cB1 = nB1; bB0 = mB0; bB1 = mB1;
        }

        *(float4*)(&part[wv][k0])       = make_float4(acc[0], acc[1], acc[2], acc[3]);
        *(float4*)(&part[wv][256 + k0]) = make_float4(acc[4], acc[5], acc[6], acc[7]);
        __syncthreads();

        float v = 0.0f;
        if (tid < KDIM) {
            float pbe = 0.0f;
            #pragma unroll
            for (int w2 = 0; w2 < NWAVE; ++w2) pbe += part[w2][tid];
            v = pbe * fmaf(xs[t], emds[tid], em0s[tid]);
        }
        if (wv < 8) {                      // only waves holding k participate
            float s = v;
            #pragma unroll
            for (int off = 1; off < 64; off <<= 1) s += __shfl_xor(s, off, 64);
            if (lane == 0) rtmp[wv] = s;
        }
        __syncthreads();
        // all threads redundantly sum 8 broadcast LDS reads (saves a barrier)
        float tot = ((rtmp[0] + rtmp[1]) + (rtmp[2] + rtmp[3]))
                  + ((rtmp[4] + rtmp[5]) + (rtmp[6] + rtmp[7]));
        const float rn = fast_rcp(tot);
        if (tid < KDIM) post[tid] = v * rn;
        __syncthreads();
    }

    if (tid < KDIM) out[b * KDIM + tid] = post[tid];
}

extern "C" void kernel_launch(void* const* d_in, const int* in_sizes, int n_in,
                              void* d_out, int out_size, void* d_ws, size_t ws_size,
                              hipStream_t stream) {
    const float* x          = (const float*)d_in[0];
    const float* prior_w    = (const float*)d_in[1];
    const float* emission_w = (const float*)d_in[2];
    const float* coeff      = (const float*)d_in[3];
    const float* bias       = (const float*)d_in[4];
    float* out              = (float*)d_out;

    const size_t need = (size_t)2 * KDIM * KDIM * sizeof(float);   // 2 MB
    if (ws_size >= need) {
        float* c2 = (float*)d_ws;
        float* b2 = c2 + (size_t)KDIM * KDIM;
        hipLaunchKernelGGL(prefold_kernel, dim3(KDIM * KDIM / 4 / 256), dim3(256),
                           0, stream, coeff, bias, c2, b2);
        hipLaunchKernelGGL((hmm_forward_kernel<true>), dim3(256), dim3(BLOCK),
                           0, stream, x, prior_w, emission_w, c2, b2, out);
    } else {
        hipLaunchKernelGGL((hmm_forward_kernel<false>), dim3(256), dim3(BLOCK),
                           0, stream, x, prior_w, emission_w, coeff, bias, out);
    }
}

// Round 8
// 1134.228 us; speedup vs baseline: 1.0707x; 1.0707x over previous
//
#include <hip/hip_runtime.h>

#define KDIM 512
#define TDIM 64
#define NWAVE 16
#define BLOCK 1024
#define LOG2E 1.4426950408889634f

typedef float v2f __attribute__((ext_vector_type(2)));

// d_ws layout (float offsets) — total ~3.1 MB, same requirement as R6 (proven fits):
#define WS_B2     0
#define WS_XCHG   (KDIM * KDIM)
#define WS_FLAGS  (WS_XCHG + 128 * 2 * 2 * 1024)
#define WS_FLOATS (WS_FLAGS + 256)

__device__ __forceinline__ float fast_exp2(float v) { return __builtin_amdgcn_exp2f(v); }
__device__ __forceinline__ float fast_rcp(float v)  { return __builtin_amdgcn_rcpf(v); }

__global__ __launch_bounds__(256) void prefold_kernel(
    const float* __restrict__ bias, float* __restrict__ b2)
{
    const int i = blockIdx.x * 256 + threadIdx.x;
    const float4 b = ((const float4*)bias)[i];
    ((float4*)b2)[i] = make_float4(b.x * LOG2E, b.y * LOG2E, b.z * LOG2E, b.w * LOG2E);
}

__device__ __forceinline__ float wave_reduce_sum(float v) {
    #pragma unroll
    for (int off = 1; off < 64; off <<= 1)
        v += __shfl_xor(v, off, 64);
    return v;
}

// Pair-split kernel (R6 structure, ~90us replay win): grid 256, 1 block/CU.
// pair = gid&127, h = gid>>7 (partner gid^128: same XCD under %8 round-robin).
// Block handles batches {2*pair, 2*pair+1} x rows [h*256,(h+1)*256).
// R8: packed-fp32 (v_pk_fma_f32 via v2f) for arg/tree/acc math — targets the
// dominant 765us VALU-issue term. No manual prefetch (R7: compiler defeats it).
__global__ __launch_bounds__(BLOCK)
__attribute__((amdgpu_waves_per_eu(4, 4)))
void hmm_pair_kernel(
    const float* __restrict__ x,           // [B, T]
    const float* __restrict__ prior_w,     // [K]
    const float* __restrict__ emission_w,  // [K, 2]
    const float* __restrict__ coeff,       // [K, K] raw
    float* __restrict__ ws,                // b2 + exchange + flags
    float* __restrict__ out)               // [B, K]
{
    __shared__ float post[2][KDIM];
    __shared__ float em0s[KDIM];
    __shared__ float emds[KDIM];
    __shared__ float part[NWAVE][2][KDIM];   // 64 KB
    __shared__ float rtmp[NWAVE];
    __shared__ float xs[2][TDIM];

    const int gid  = blockIdx.x;
    const int pair = gid & 127;
    const int h    = gid >> 7;             // row half
    const int b0   = 2 * pair;
    const int tid  = threadIdx.x;
    const int lane = tid & 63;
    const int wv   = tid >> 6;
    const int k0   = 4 * lane;
    const int u    = tid >> 9;             // epilogue batch index
    const int k    = tid & 511;            // epilogue k index

    const float* bb = ws + WS_B2;
    int* flags   = (int*)(ws + WS_FLAGS);
    int* my_flag = flags + (pair * 2 + h);
    int* pr_flag = flags + (pair * 2 + (1 - h));
    float* my_slot = ws + WS_XCHG + (size_t)(pair * 2 + h) * 2048;
    float* pr_slot = ws + WS_XCHG + (size_t)(pair * 2 + (1 - h)) * 2048;

    if (tid < 2 * TDIM) xs[tid >> 6][tid & 63] = x[(b0 + (tid >> 6)) * TDIM + (tid & 63)];
    if (tid < KDIM) {
        const float w0 = emission_w[2 * tid + 0];
        const float w1 = emission_w[2 * tid + 1];
        const float e0 = 1.0f / (1.0f + fast_exp2((w1 - w0) * LOG2E));
        em0s[tid] = e0;
        emds[tid] = 1.0f - 2.0f * e0;
    }
    __syncthreads();

    // ---- t = 0: both batches, full K, locally ----
    {
        const float x0 = xs[u][0];
        float v = fast_exp2(prior_w[k] * LOG2E) * fmaf(x0, emds[k], em0s[k]);
        float s = wave_reduce_sum(v);       // waves 0-7: batch0, 8-15: batch1
        if (lane == 0) rtmp[wv] = s;
        __syncthreads();
        const float* rb = &rtmp[u * 8];
        const float tot = ((rb[0] + rb[1]) + (rb[2] + rb[3]))
                        + ((rb[4] + rb[5]) + (rb[6] + rb[7]));
        post[u][k] = v * fast_rcp(tot);
        __syncthreads();
    }

    // ---- steps t = 1 .. T-1 ----
    for (int t = 1; t < TDIM; ++t) {
        v2f acc[2][4];
        #pragma unroll
        for (int uu = 0; uu < 2; ++uu)
            #pragma unroll
            for (int q = 0; q < 4; ++q) acc[uu][q] = (v2f){0.0f, 0.0f};

        // wave wv: row pairs (jA = h*256 + wv + 32*i, jB = jA + 16), i<8
        const float* pc = coeff + (size_t)(h * 256 + wv) * KDIM + k0;
        const float* pb = bb    + (size_t)(h * 256 + wv) * KDIM + k0;

        #pragma unroll 1
        for (int i = 0; i < 8; ++i) {
            const int jA = h * 256 + wv + 32 * i;
            const float4 cA0 = *(const float4*)pc;
            const float4 cA1 = *(const float4*)(pc + 256);
            const float4 cB0 = *(const float4*)(pc + 16 * KDIM);
            const float4 cB1 = *(const float4*)(pc + 16 * KDIM + 256);
            const float4 bA0 = *(const float4*)pb;
            const float4 bA1 = *(const float4*)(pb + 256);
            const float4 bB0 = *(const float4*)(pb + 16 * KDIM);
            const float4 bB1 = *(const float4*)(pb + 16 * KDIM + 256);
            pc += 32 * KDIM; pb += 32 * KDIM;

            const v2f cav[4] = {{cA0.x, cA0.y}, {cA0.z, cA0.w}, {cA1.x, cA1.y}, {cA1.z, cA1.w}};
            const v2f cbv[4] = {{cB0.x, cB0.y}, {cB0.z, cB0.w}, {cB1.x, cB1.y}, {cB1.z, cB1.w}};
            const v2f bav[4] = {{bA0.x, bA0.y}, {bA0.z, bA0.w}, {bA1.x, bA1.y}, {bA1.z, bA1.w}};
            const v2f bbv[4] = {{bB0.x, bB0.y}, {bB0.z, bB0.w}, {bB1.x, bB1.y}, {bB1.z, bB1.w}};

            float p[2][2];
            p[0][0] = post[0][jA]; p[0][1] = post[0][jA + 16];
            p[1][0] = post[1][jA]; p[1][1] = post[1][jA + 16];

            v2f ev[2][2][4];   // [uu][rowAB][q]
            float s[4];
            #pragma unroll
            for (int uu = 0; uu < 2; ++uu) {
                const float pAL = p[uu][0] * LOG2E;
                const float pBL = p[uu][1] * LOG2E;
                const v2f pAv = {pAL, pAL};
                const v2f pBv = {pBL, pBL};
                #pragma unroll
                for (int q = 0; q < 4; ++q) {
                    const v2f aA = __builtin_elementwise_fma(pAv, cav[q], bav[q]);
                    const v2f aB = __builtin_elementwise_fma(pBv, cbv[q], bbv[q]);
                    v2f eA, eB;
                    eA.x = fast_exp2(aA.x); eA.y = fast_exp2(aA.y);
                    eB.x = fast_exp2(aB.x); eB.y = fast_exp2(aB.y);
                    ev[uu][0][q] = eA;
                    ev[uu][1][q] = eB;
                }
                const v2f tA = (ev[uu][0][0] + ev[uu][0][1]) + (ev[uu][0][2] + ev[uu][0][3]);
                const v2f tB = (ev[uu][1][0] + ev[uu][1][1]) + (ev[uu][1][2] + ev[uu][1][3]);
                s[uu * 2 + 0] = tA.x + tA.y;
                s[uu * 2 + 1] = tB.x + tB.y;
            }
            // 4 independent butterfly chains, interleaved
            #pragma unroll
            for (int off = 1; off < 64; off <<= 1) {
                s[0] += __shfl_xor(s[0], off, 64);
                s[1] += __shfl_xor(s[1], off, 64);
                s[2] += __shfl_xor(s[2], off, 64);
                s[3] += __shfl_xor(s[3], off, 64);
            }
            #pragma unroll
            for (int uu = 0; uu < 2; ++uu) {
                const float scA = p[uu][0] * fast_rcp(s[uu * 2 + 0]);
                const float scB = p[uu][1] * fast_rcp(s[uu * 2 + 1]);
                const v2f scAv = {scA, scA};
                const v2f scBv = {scB, scB};
                #pragma unroll
                for (int q = 0; q < 4; ++q) {
                    acc[uu][q] = __builtin_elementwise_fma(scAv, ev[uu][0][q], acc[uu][q]);
                    acc[uu][q] = __builtin_elementwise_fma(scBv, ev[uu][1][q], acc[uu][q]);
                }
            }
        }

        *(float4*)(&part[wv][0][k0])       = make_float4(acc[0][0].x, acc[0][0].y, acc[0][1].x, acc[0][1].y);
        *(float4*)(&part[wv][0][256 + k0]) = make_float4(acc[0][2].x, acc[0][2].y, acc[0][3].x, acc[0][3].y);
        *(float4*)(&part[wv][1][k0])       = make_float4(acc[1][0].x, acc[1][0].y, acc[1][1].x, acc[1][1].y);
        *(float4*)(&part[wv][1][256 + k0]) = make_float4(acc[1][2].x, acc[1][2].y, acc[1][3].x, acc[1][3].y);
        __syncthreads();

        // half-pbe for (u, k)
        float pbe = 0.0f;
        #pragma unroll
        for (int w2 = 0; w2 < NWAVE; ++w2) pbe += part[w2][u][k];

        // exchange with partner
        float* slot = my_slot + (t & 1) * 1024;
        __hip_atomic_store(&slot[tid], pbe, __ATOMIC_RELAXED, __HIP_MEMORY_SCOPE_AGENT);
        __syncthreads();   // drains vmcnt -> all agent stores complete
        if (tid == 0) {
            __hip_atomic_store(my_flag, t, __ATOMIC_RELEASE, __HIP_MEMORY_SCOPE_AGENT);
            int f = __hip_atomic_load(pr_flag, __ATOMIC_ACQUIRE, __HIP_MEMORY_SCOPE_AGENT);
            while (f < t) {
                __builtin_amdgcn_s_sleep(1);
                f = __hip_atomic_load(pr_flag, __ATOMIC_ACQUIRE, __HIP_MEMORY_SCOPE_AGENT);
            }
        }
        __syncthreads();
        const float* pslot = pr_slot + (t & 1) * 1024;
        const float other = __hip_atomic_load(&pslot[tid], __ATOMIC_RELAXED, __HIP_MEMORY_SCOPE_AGENT);

        float v = (pbe + other) * fmaf(xs[u][t], emds[k], em0s[k]);
        float s = wave_reduce_sum(v);
        if (lane == 0) rtmp[wv] = s;
        __syncthreads();
        const float* rb = &rtmp[u * 8];
        const float tot = ((rb[0] + rb[1]) + (rb[2] + rb[3]))
                        + ((rb[4] + rb[5]) + (rb[6] + rb[7]));
        post[u][k] = v * fast_rcp(tot);
        __syncthreads();
    }

    if (tid < KDIM) out[(size_t)(b0 + h) * KDIM + tid] = post[h][tid];
}

// ---------- fallback: R4 single-batch kernel (no workspace needed) ----------
__global__ __launch_bounds__(BLOCK)
__attribute__((amdgpu_waves_per_eu(4, 4)))
void hmm_forward_kernel(
    const float* __restrict__ x, const float* __restrict__ prior_w,
    const float* __restrict__ emission_w, const float* __restrict__ coeff,
    const float* __restrict__ bias, float* __restrict__ out)
{
    __shared__ float post[KDIM];
    __shared__ float em0s[KDIM];
    __shared__ float emds[KDIM];
    __shared__ float part[NWAVE][KDIM];
    __shared__ float rtmp[NWAVE];
    __shared__ float xs[TDIM];

    const int b = blockIdx.x, tid = threadIdx.x, lane = tid & 63, wv = tid >> 6;
    const int k0 = 4 * lane;

    if (tid < TDIM) xs[tid] = x[b * TDIM + tid];
    if (tid < KDIM) {
        const float w0 = emission_w[2 * tid + 0];
        const float w1 = emission_w[2 * tid + 1];
        const float e0 = 1.0f / (1.0f + fast_exp2((w1 - w0) * LOG2E));
        em0s[tid] = e0;
        emds[tid] = 1.0f - 2.0f * e0;
    }
    __syncthreads();
    {
        const float x0 = xs[0];
        float v = 0.0f;
        if (tid < KDIM)
            v = fast_exp2(prior_w[tid] * LOG2E) * fmaf(x0, emds[tid], em0s[tid]);
        float s = wave_reduce_sum(v);
        if (lane == 0) rtmp[wv] = s;
        __syncthreads();
        if (wv == 0) {
            float t2 = (lane < NWAVE) ? rtmp[lane] : 0.0f;
            #pragma unroll
            for (int off = 1; off < NWAVE; off <<= 1) t2 += __shfl_xor(t2, off, 64);
            if (lane == 0) rtmp[0] = t2;
        }
        __syncthreads();
        const float rn = fast_rcp(rtmp[0]);
        if (tid < KDIM) post[tid] = v * rn;
        __syncthreads();
    }
    for (int t = 1; t < TDIM; ++t) {
        float acc[8];
        #pragma unroll
        for (int i = 0; i < 8; ++i) acc[i] = 0.0f;
        const float* cA = coeff + (size_t)wv * KDIM + k0;
        const float* bA = bias  + (size_t)wv * KDIM + k0;
        #pragma unroll 1
        for (int i = 0; i < 16; ++i) {
            const float4 cA0 = *(const float4*)cA;
            const float4 cA1 = *(const float4*)(cA + 256);
            const float4 cB0 = *(const float4*)(cA + 16 * KDIM);
            const float4 cB1 = *(const float4*)(cA + 16 * KDIM + 256);
            const float4 bA0 = *(const float4*)bA;
            const float4 bA1 = *(const float4*)(bA + 256);
            const float4 bB0 = *(const float4*)(bA + 16 * KDIM);
            const float4 bB1 = *(const float4*)(bA + 16 * KDIM + 256);
            cA += 32 * KDIM; bA += 32 * KDIM;
            const float pA = post[wv + 32 * i];
            const float pB = post[wv + 16 + 32 * i];
            const float eA0 = fast_exp2(fmaf(pA, cA0.x, bA0.x) * LOG2E);
            const float eA1 = fast_exp2(fmaf(pA, cA0.y, bA0.y) * LOG2E);
            const float eA2 = fast_exp2(fmaf(pA, cA0.z, bA0.z) * LOG2E);
            const float eA3 = fast_exp2(fmaf(pA, cA0.w, bA0.w) * LOG2E);
            const float eA4 = fast_exp2(fmaf(pA, cA1.x, bA1.x) * LOG2E);
            const float eA5 = fast_exp2(fmaf(pA, cA1.y, bA1.y) * LOG2E);
            const float eA6 = fast_exp2(fmaf(pA, cA1.z, bA1.z) * LOG2E);
            const float eA7 = fast_exp2(fmaf(pA, cA1.w, bA1.w) * LOG2E);
            const float eB0 = fast_exp2(fmaf(pB, cB0.x, bB0.x) * LOG2E);
            const float eB1 = fast_exp2(fmaf(pB, cB0.y, bB0.y) * LOG2E);
            const float eB2 = fast_exp2(fmaf(pB, cB0.z, bB0.z) * LOG2E);
            const float eB3 = fast_exp2(fmaf(pB, cB0.w, bB0.w) * LOG2E);
            const float eB4 = fast_exp2(fmaf(pB, cB1.x, bB1.x) * LOG2E);
            const float eB5 = fast_exp2(fmaf(pB, cB1.y, bB1.y) * LOG2E);
            const float eB6 = fast_exp2(fmaf(pB, cB1.z, bB1.z) * LOG2E);
            const float eB7 = fast_exp2(fmaf(pB, cB1.w, bB1.w) * LOG2E);
            float sA = ((eA0 + eA1) + (eA2 + eA3)) + ((eA4 + eA5) + (eA6 + eA7));
            float sB = ((eB0 + eB1) + (eB2 + eB3)) + ((eB4 + eB5) + (eB6 + eB7));
            #pragma unroll
            for (int off = 1; off < 64; off <<= 1) {
                sA += __shfl_xor(sA, off, 64);
                sB += __shfl_xor(sB, off, 64);
            }
            const float scA = pA * fast_rcp(sA);
            const float scB = pB * fast_rcp(sB);
            acc[0] = fmaf(scA, eA0, acc[0]); acc[0] = fmaf(scB, eB0, acc[0]);
            acc[1] = fmaf(scA, eA1, acc[1]); acc[1] = fmaf(scB, eB1, acc[1]);
            acc[2] = fmaf(scA, eA2, acc[2]); acc[2] = fmaf(scB, eB2, acc[2]);
            acc[3] = fmaf(scA, eA3, acc[3]); acc[3] = fmaf(scB, eB3, acc[3]);
            acc[4] = fmaf(scA, eA4, acc[4]); acc[4] = fmaf(scB, eB4, acc[4]);
            acc[5] = fmaf(scA, eA5, acc[5]); acc[5] = fmaf(scB, eB5, acc[5]);
            acc[6] = fmaf(scA, eA6, acc[6]); acc[6] = fmaf(scB, eB6, acc[6]);
            acc[7] = fmaf(scA, eA7, acc[7]); acc[7] = fmaf(scB, eB7, acc[7]);
        }
        *(float4*)(&part[wv][k0])       = make_float4(acc[0], acc[1], acc[2], acc[3]);
        *(float4*)(&part[wv][256 + k0]) = make_float4(acc[4], acc[5], acc[6], acc[7]);
        __syncthreads();
        float v = 0.0f;
        if (tid < KDIM) {
            float pbe = 0.0f;
            #pragma unroll
            for (int w2 = 0; w2 < NWAVE; ++w2) pbe += part[w2][tid];
            v = pbe * fmaf(xs[t], emds[tid], em0s[tid]);
        }
        float s = wave_reduce_sum(v);
        if (lane == 0) rtmp[wv] = s;
        __syncthreads();
        if (wv == 0) {
            float t2 = (lane < NWAVE) ? rtmp[lane] : 0.0f;
            #pragma unroll
            for (int off = 1; off < NWAVE; off <<= 1) t2 += __shfl_xor(t2, off, 64);
            if (lane == 0) rtmp[0] = t2;
        }
        __syncthreads();
        const float rn = fast_rcp(rtmp[0]);
        if (tid < KDIM) post[tid] = v * rn;
        __syncthreads();
    }
    if (tid < KDIM) out[b * KDIM + tid] = post[tid];
}

extern "C" void kernel_launch(void* const* d_in, const int* in_sizes, int n_in,
                              void* d_out, int out_size, void* d_ws, size_t ws_size,
                              hipStream_t stream) {
    const float* x          = (const float*)d_in[0];
    const float* prior_w    = (const float*)d_in[1];
    const float* emission_w = (const float*)d_in[2];
    const float* coeff      = (const float*)d_in[3];
    const float* bias       = (const float*)d_in[4];
    float* out              = (float*)d_out;

    if (ws_size >= (size_t)WS_FLOATS * sizeof(float)) {
        float* ws = (float*)d_ws;
        hipLaunchKernelGGL(prefold_kernel, dim3(KDIM * KDIM / 4 / 256), dim3(256),
                           0, stream, bias, ws + WS_B2);
        hipLaunchKernelGGL(hmm_pair_kernel, dim3(256), dim3(BLOCK), 0, stream,
                           x, prior_w, emission_w, coeff, ws, out);
    } else {
        hipLaunchKernelGGL(hmm_forward_kernel, dim3(256), dim3(BLOCK), 0, stream,
                           x, prior_w, emission_w, coeff, bias, out);
    }
}